// Round 1
// baseline (1327.183 us; speedup 1.0000x reference)
//
#include <hip/hip_runtime.h>
#include <hip/hip_bf16.h>

// ---------------------------------------------------------------------------
// LinearSystem: states/obs of a driven linear state-space model.
//   B=64, T=1024, S=512, I=256, O=256.
// Strategy: chunked parallel scan (32 chunks x 32 steps) entirely in bf16 MFMA
// with f32 accumulation. One generic 64x64 tiled GEMM kernel drives all stages.
// ---------------------------------------------------------------------------

typedef short bfrag __attribute__((ext_vector_type(8)));   // 8 x bf16 bits (4 VGPR)
typedef float f32x4 __attribute__((ext_vector_type(4)));

__device__ __host__ inline unsigned short f2bf(float f) {
    union { float f; unsigned u; } x; x.f = f;
    unsigned r = x.u + 0x7fffu + ((x.u >> 16) & 1u);   // RNE
    return (unsigned short)(r >> 16);
}

struct GemmDesc {
    const void* a0; const void* a1;          // A sources (k < ksplit -> a0)
    const unsigned short* b;                 // B, bf16 bits, (N,K) row-major (B^T form)
    float* c;                                // f32 C (nullable)
    unsigned short* cm;                      // bf16 mirror of C (nullable)
    long a0_base, a0_os, a0_is, a0_ic;       // row map: (r/ic)*os + (r%ic)*is
    long a1_base, a1_os, a1_is, a1_ic;
    long a_zq, a_zr;                         // z offsets: (z/zdiv)*zq + (z%zdiv)*zr
    long b_base, b_ldb, b_zq, b_zr;
    long c_base, c_os, c_is, c_ic, c_zq, c_zr;
    long cm_base;
    long zdiv;
    int a0_f32, a1_f32, ksplit, K, beta;
};

__global__ __launch_bounds__(256) void gemm_k(GemmDesc d) {
    __shared__ __align__(16) unsigned short As[64 * 64];
    __shared__ __align__(16) unsigned short Bs[64 * 64];
    const int tid = threadIdx.x;
    const int lane = tid & 63;
    const int w = tid >> 6;
    const int wm = w >> 1, wn = w & 1;      // 2x2 waves, each 32x32 output
    const long z = blockIdx.z;
    const long zq = z / d.zdiv, zr = z % d.zdiv;
    const int row0 = blockIdx.y * 64;
    const int col0 = blockIdx.x * 64;
    const int srow = tid >> 2;               // staging row 0..63
    const int skq  = (tid & 3) << 4;         // staging k offset (16 elems/thread)
    const int swzw = (srow & 7) << 3;        // XOR swizzle (elements; == bytes>>1 *16)

    const long ar = row0 + srow;
    const long za = zq * d.a_zq + zr * d.a_zr;
    const long a0ro = d.a0_base + za + (ar / d.a0_ic) * d.a0_os + (ar % d.a0_ic) * d.a0_is;
    long a1ro = 0;
    if (d.a1) a1ro = d.a1_base + za + (ar / d.a1_ic) * d.a1_os + (ar % d.a1_ic) * d.a1_is;
    const long bro = d.b_base + zq * d.b_zq + zr * d.b_zr + (long)(col0 + srow) * d.b_ldb;

    f32x4 acc[2][2] = {};
    union { bfrag v; unsigned short h[8]; } t0, t1;

    for (int k0 = 0; k0 < d.K; k0 += 64) {
        __syncthreads();
        // ---- stage A: 16 elems at (row0+srow, k0+skq) ----
        {
            const int kg = k0 + skq;
            if (kg < d.ksplit) {
                if (d.a0_f32) {
                    const float* p = (const float*)d.a0 + a0ro + kg;
                    f32x4 x0 = *(const f32x4*)(p + 0), x1 = *(const f32x4*)(p + 4);
                    f32x4 x2 = *(const f32x4*)(p + 8), x3 = *(const f32x4*)(p + 12);
#pragma unroll
                    for (int q = 0; q < 4; ++q) {
                        t0.h[q]     = f2bf(x0[q]); t0.h[4 + q] = f2bf(x1[q]);
                        t1.h[q]     = f2bf(x2[q]); t1.h[4 + q] = f2bf(x3[q]);
                    }
                } else {
                    const unsigned short* p = (const unsigned short*)d.a0 + a0ro + kg;
                    t0.v = *(const bfrag*)(p); t1.v = *(const bfrag*)(p + 8);
                }
            } else {
                const int kl = kg - d.ksplit;
                if (d.a1_f32) {
                    const float* p = (const float*)d.a1 + a1ro + kl;
                    f32x4 x0 = *(const f32x4*)(p + 0), x1 = *(const f32x4*)(p + 4);
                    f32x4 x2 = *(const f32x4*)(p + 8), x3 = *(const f32x4*)(p + 12);
#pragma unroll
                    for (int q = 0; q < 4; ++q) {
                        t0.h[q]     = f2bf(x0[q]); t0.h[4 + q] = f2bf(x1[q]);
                        t1.h[q]     = f2bf(x2[q]); t1.h[4 + q] = f2bf(x3[q]);
                    }
                } else {
                    const unsigned short* p = (const unsigned short*)d.a1 + a1ro + kl;
                    t0.v = *(const bfrag*)(p); t1.v = *(const bfrag*)(p + 8);
                }
            }
            *(bfrag*)&As[srow * 64 + ((skq + 0) ^ swzw)] = t0.v;
            *(bfrag*)&As[srow * 64 + ((skq + 8) ^ swzw)] = t1.v;
            // ---- stage B: B is (N,K) row-major ----
            const unsigned short* pb = d.b + bro + k0 + skq;
            bfrag b0 = *(const bfrag*)(pb), b1 = *(const bfrag*)(pb + 8);
            *(bfrag*)&Bs[srow * 64 + ((skq + 0) ^ swzw)] = b0;
            *(bfrag*)&Bs[srow * 64 + ((skq + 8) ^ swzw)] = b1;
        }
        __syncthreads();
        // ---- compute 2x2 x (K=64) ----
#pragma unroll
        for (int ks = 0; ks < 2; ++ks) {
            bfrag af[2], bfm[2];
#pragma unroll
            for (int mt = 0; mt < 2; ++mt) {
                const int r = wm * 32 + mt * 16 + (lane & 15);
                const int kk = ks * 32 + ((lane >> 4) << 3);
                af[mt] = *(const bfrag*)&As[r * 64 + (kk ^ ((r & 7) << 3))];
            }
#pragma unroll
            for (int nt = 0; nt < 2; ++nt) {
                const int r = wn * 32 + nt * 16 + (lane & 15);
                const int kk = ks * 32 + ((lane >> 4) << 3);
                bfm[nt] = *(const bfrag*)&Bs[r * 64 + (kk ^ ((r & 7) << 3))];
            }
#pragma unroll
            for (int mt = 0; mt < 2; ++mt)
#pragma unroll
                for (int nt = 0; nt < 2; ++nt)
                    acc[mt][nt] = __builtin_amdgcn_mfma_f32_16x16x32_bf16(
                        af[mt], bfm[nt], acc[mt][nt], 0, 0, 0);
        }
    }
    // ---- epilogue: C/D layout col=lane&15, row=(lane>>4)*4+j ----
    const long zc = zq * d.c_zq + zr * d.c_zr;
#pragma unroll
    for (int mt = 0; mt < 2; ++mt) {
        const int rb = row0 + wm * 32 + mt * 16 + ((lane >> 4) << 2);
#pragma unroll
        for (int nt = 0; nt < 2; ++nt) {
            const int cc = col0 + wn * 32 + nt * 16 + (lane & 15);
#pragma unroll
            for (int j = 0; j < 4; ++j) {
                const long r = rb + j;
                const long off = zc + (r / d.c_ic) * d.c_os + (r % d.c_ic) * d.c_is + cc;
                float v = acc[mt][nt][j];
                if (d.c) {
                    float* cp = d.c + d.c_base + off;
                    if (d.beta) v += *cp;
                    *cp = v;
                }
                if (d.cm) d.cm[d.cm_base + off] = f2bf(v);
            }
        }
    }
}

// Build bf16 operator matrices: BopD (512x768)=[B_mat|sqrt_S_W], BopO (256x768)=[H|sqrt_S_V],
// G1 = F, Gt1 = F^T.
__global__ void build_ops_k(const float* F, const float* Bm, const float* H,
                            const float* sW, const float* sV,
                            unsigned short* bopd, unsigned short* bopo,
                            unsigned short* G1, unsigned short* Gt1) {
    int i = blockIdx.x * 256 + threadIdx.x;
    const int n1 = 512 * 768, n2 = 256 * 768, n3 = 512 * 512;
    if (i < n1) { int n = i / 768, k = i % 768;
        bopd[i] = f2bf(k < 256 ? Bm[n * 256 + k] : sW[n * 512 + (k - 256)]); return; }
    i -= n1;
    if (i < n2) { int o = i / 768, k = i % 768;
        bopo[i] = f2bf(k < 512 ? H[o * 512 + k] : sV[o * 256 + (k - 512)]); return; }
    i -= n2;
    if (i < n3) { G1[i] = f2bf(F[i]); return; }
    i -= n3;
    if (i < n3) { int r = i / 512, c = i % 512; Gt1[i] = f2bf(F[c * 512 + r]); }
}

// Copy rows of 512 f32 (generic strided src) to contiguous f32 + bf16 mirror.
__global__ void copy_rows_k(const float* src, long s_base, long s_os, long s_is, long s_ic,
                            float* dstf, unsigned short* dstm, long d_base, long n) {
    long i = (long)blockIdx.x * 256 + threadIdx.x;
    const long stride = (long)gridDim.x * 256;
    for (; i < n; i += stride) {
        const long r = i >> 9;
        const long kc = i & 511;
        const float v = src[s_base + (r / s_ic) * s_os + (r % s_ic) * s_is + kc];
        dstf[d_base + i] = v;
        dstm[d_base + i] = f2bf(v);
    }
}

static GemmDesc D0() {
    GemmDesc d = {};
    d.a0_ic = 1; d.a1_ic = 1; d.c_ic = 1;
    d.zdiv = 1L << 40;
    d.ksplit = 1 << 30;
    d.b_ldb = 512; d.K = 512;
    return d;
}

extern "C" void kernel_launch(void* const* d_in, const int* in_sizes, int n_in,
                              void* d_out, int out_size, void* d_ws, size_t ws_size,
                              hipStream_t stream) {
    const float* st0 = (const float*)d_in[0];   // state   (64,512)
    const float* inp = (const float*)d_in[1];   // inputs  (64,1024,256)
    const float* Wn  = (const float*)d_in[2];   // W_noise (64,1024,512)
    const float* Vn  = (const float*)d_in[3];   // V_noise (64,1024,256)
    const float* F   = (const float*)d_in[4];   // F       (512,512)
    const float* Bm  = (const float*)d_in[5];   // B_mat   (512,256)
    const float* H   = (const float*)d_in[6];   // H       (256,512)
    const float* sW  = (const float*)d_in[7];   // sqrt_S_W(512,512)
    const float* sV  = (const float*)d_in[8];   // sqrt_S_V(256,256)

    float* states = (float*)d_out;              // (64,1024,512)
    float* obs    = states + 33554432L;         // (64,1024,256)

    const long MS = 262144;   // 512*512
    const long CB = 32768;    // 64*512 carry block

    // ws layout (bf16 = unsigned short bits)
    unsigned short* Smir = (unsigned short*)d_ws;       // 33,554,432 elems
    unsigned short* G    = Smir + 33554432L;            // G[j-1] = F^j, j=1..32
    unsigned short* Gt   = G + 32 * MS;                 // Gt[j-1] = (F^j)^T
    unsigned short* Qb   = Gt + 32 * MS;                // F^{64},F^{128},F^{256},F^{512}
    unsigned short* Qtb  = Qb + 4 * MS;                 // transposes (first 3)
    unsigned short* BopD = Qtb + 3 * MS;                // 512*768
    unsigned short* BopO = BopD + 512 * 768;            // 256*768
    float* a0f = (float*)(BopO + 256 * 768);            // 32*64*512 f32
    float* a1f = a0f + 32 * CB;
    unsigned short* a0m = (unsigned short*)(a1f + 32 * CB);
    unsigned short* a1m = a0m + 32 * CB;
    (void)ws_size; (void)in_sizes; (void)n_in; (void)out_size;

    auto launch = [&](const GemmDesc& d, int gx, int gy, int gz) {
        gemm_k<<<dim3(gx, gy, gz), dim3(256), 0, stream>>>(d);
    };

    // 1) operator matrices
    build_ops_k<<<dim3((512*768 + 256*768 + 2*512*512) / 256), dim3(256), 0, stream>>>(
        F, Bm, H, sW, sV, BopD, BopO, G, Gt);

    // 2) powers G_j = F^j (and transposes) by doubling: G_{m+j} = G_j @ Gt_m^T
    for (int m = 1; m <= 16; m <<= 1) {
        GemmDesc d = D0();
        d.a0 = G; d.a0_os = 512; d.a_zr = MS;
        d.b = Gt; d.b_base = (long)(m - 1) * MS;
        d.cm = G; d.cm_base = (long)m * MS; d.c_os = 512; d.c_zr = MS;
        launch(d, 8, 8, m);
        GemmDesc e = D0();
        e.a0 = Gt; e.a0_base = (long)(m - 1) * MS; e.a0_os = 512;
        e.b = G; e.b_zr = MS;
        e.cm = Gt; e.cm_base = (long)m * MS; e.c_os = 512; e.c_zr = MS;
        launch(e, 8, 8, m);
    }
    // Q chain: E = F^32 (=G[31]); squares F^64.. via gemm_bt(Q, Qt)
    auto ql = [&](const unsigned short* A, long ab, const unsigned short* B, long bb,
                  unsigned short* Cm, long cb) {
        GemmDesc d = D0();
        d.a0 = A; d.a0_base = ab; d.a0_os = 512;
        d.b = B; d.b_base = bb;
        d.cm = Cm; d.cm_base = cb; d.c_os = 512;
        launch(d, 8, 8, 1);
    };
    ql(G, 31 * MS, Gt, 31 * MS, Qb, 0);          // F^64
    ql(Gt, 31 * MS, G, 31 * MS, Qtb, 0);
    ql(Qb, 0, Qtb, 0, Qb, MS);                   // F^128
    ql(Qtb, 0, Qb, 0, Qtb, MS);
    ql(Qb, MS, Qtb, MS, Qb, 2 * MS);             // F^256
    ql(Qtb, MS, Qb, MS, Qtb, 2 * MS);
    ql(Qb, 2 * MS, Qtb, 2 * MS, Qb, 3 * MS);     // F^512

    // 3) drive = [inputs | W_noise] @ BopD^T  -> states (f32) + mirror
    {
        GemmDesc d = D0();
        d.a0 = inp; d.a0_f32 = 1; d.a0_os = 256;
        d.a1 = Wn;  d.a1_f32 = 1; d.a1_os = 512;
        d.ksplit = 256; d.K = 768;
        d.b = BopD; d.b_ldb = 768;
        d.c = states; d.c_os = 512;
        d.cm = Smir;
        launch(d, 8, 1024, 1);
    }

    // 4) phase 1: local scans, 31 sequential steps over all 32 chunks at once.
    //    rows r -> (b = r/32, c = r%32); element = b*524288 + c*16384 + k*512
    for (int k = 1; k < 32; ++k) {
        GemmDesc d = D0();
        d.a0 = Smir; d.a0_base = (long)(k - 1) * 512;
        d.a0_ic = 32; d.a0_is = 16384; d.a0_os = 524288;
        d.b = G;  // F^1
        d.c = states; d.c_base = (long)k * 512;
        d.c_ic = 32; d.c_is = 16384; d.c_os = 524288; d.beta = 1;
        d.cm = Smir; d.cm_base = (long)k * 512;
        launch(d, 8, 32, 1);
    }

    // 5) carry sequence e: e[0]=s0, e[c]=L[c-1, 31]
    copy_rows_k<<<dim3(128), dim3(256), 0, stream>>>(st0, 0, 512, 0, 1, a0f, a0m, 0, 32768);
    copy_rows_k<<<dim3(3968), dim3(256), 0, stream>>>(states, 31L * 512, 16384, 524288, 64,
                                                      a0f, a0m, CB, 1984L * 512);

    // 6) Kogge-Stone over 32 affine elements: a_c += a_{c-s} @ (F^{32s})^T
    {
        float* cur = a0f; unsigned short* curm = a0m;
        float* nxt = a1f; unsigned short* nxtm = a1m;
        for (int s = 1; s <= 16; s <<= 1) {
            copy_rows_k<<<dim3(4096), dim3(256), 0, stream>>>(cur, 0, 512, 0, 1,
                                                              nxt, nxtm, 0, 32L * CB);
            GemmDesc d = D0();
            d.a0 = curm; d.a0_os = 512; d.a_zr = CB;
            const unsigned short* qm; long qb;
            if (s == 1)      { qm = G;  qb = 31 * MS; }
            else if (s == 2) { qm = Qb; qb = 0; }
            else if (s == 4) { qm = Qb; qb = MS; }
            else if (s == 8) { qm = Qb; qb = 2 * MS; }
            else             { qm = Qb; qb = 3 * MS; }
            d.b = qm; d.b_base = qb;
            d.c = nxt; d.c_base = (long)s * CB; d.c_os = 512; d.c_zr = CB; d.beta = 1;
            d.cm = nxtm; d.cm_base = (long)s * CB;
            launch(d, 8, 1, 32 - s);
            float* tf = cur; cur = nxt; nxt = tf;
            unsigned short* tm = curm; curm = nxtm; nxtm = tm;
        }
        // final carries (init_c) are in `cur`/`curm` (= a1f/a1m after 5 rounds)

        // 7) phase 3: states[c,k] += init_c @ (F^{k+1})^T, z = c*32 + k
        GemmDesc d = D0();
        d.a0 = curm; d.a0_os = 512; d.a_zq = CB; d.zdiv = 32;
        d.b = G; d.b_zr = MS;
        d.c = states; d.c_zq = 16384; d.c_zr = 512; d.c_os = 524288; d.beta = 1;
        d.cm = Smir;
        launch(d, 8, 1, 1024);
    }

    // 8) obs = [states_bf16 | V_noise] @ BopO^T
    {
        GemmDesc d = D0();
        d.a0 = Smir; d.a0_os = 512;
        d.a1 = Vn; d.a1_f32 = 1; d.a1_os = 256;
        d.ksplit = 512; d.K = 768;
        d.b = BopO; d.b_ldb = 768;
        d.c = obs; d.c_os = 256;
        launch(d, 4, 1024, 1);
    }
}

// Round 2
// 803.781 us; speedup vs baseline: 1.6512x; 1.6512x over previous
//
#include <hip/hip_runtime.h>
#include <hip/hip_bf16.h>

// ---------------------------------------------------------------------------
// LinearSystem: chunked parallel scan (64 chunks x 16 steps), bf16 MFMA.
// Round 2: wide-N GEMM template (A-refetch fix), bf16-only intermediate states
// (f32 written once in phase 3), powers write transpose in-epilogue.
// ---------------------------------------------------------------------------

typedef short bfrag __attribute__((ext_vector_type(8)));   // 8 x bf16 bits
typedef float f32x4 __attribute__((ext_vector_type(4)));

__device__ __host__ inline unsigned short f2bf(float f) {
    union { float f; unsigned u; } x; x.f = f;
    unsigned r = x.u + 0x7fffu + ((x.u >> 16) & 1u);   // RNE
    return (unsigned short)(r >> 16);
}
__device__ inline float bf2f(unsigned short h) {
    union { unsigned u; float f; } x; x.u = ((unsigned)h) << 16;
    return x.f;
}

struct GemmDesc {
    const void* a0; const void* a1;          // A sources (k < ksplit -> a0)
    const unsigned short* b;                 // B, bf16, (N,K) row-major (B^T form)
    float* c;                                // f32 C (nullable)
    unsigned short* cm;                      // bf16 mirror of C (nullable)
    unsigned short* cmT;                     // bf16 transposed mirror (512x512 mats)
    long a0_base, a0_os, a0_is, a0_ic;       // row map: (r/ic)*os + (r%ic)*is
    long a1_base, a1_os, a1_is, a1_ic;
    long a_zq, a_zr;                         // z offsets: (z/zdiv)*zq + (z%zdiv)*zr
    long b_base, b_ldb, b_zq, b_zr;
    long c_base, c_os, c_is, c_ic, c_zq, c_zr;
    long cm_base, cmT_base;
    long zdiv;
    int a0_f32, a1_f32, ksplit, K, beta;     // beta: 0 none, 1 f32 from c, 2 bf16 from cm
};

template<int NT>
__global__ __launch_bounds__(256) void gemm_k(GemmDesc d) {
    __shared__ __align__(16) unsigned short As[64 * 64];
    __shared__ __align__(16) unsigned short Bs[NT * 64 * 64];
    const int tid = threadIdx.x;
    const int lane = tid & 63;
    const int w = tid >> 6;
    const int wm = w >> 1, wn = w & 1;      // 2x2 waves over the 64x64 subtile
    const long z = blockIdx.z;
    const long zq = z / d.zdiv, zr = z % d.zdiv;
    const int row0 = blockIdx.y * 64;
    const int col0 = blockIdx.x * (NT * 64);
    const int srow = tid >> 2;               // staging row 0..63
    const int skq  = (tid & 3) << 4;         // staging k offset (16 elems/thread)
    const int swzw = (srow & 7) << 3;        // XOR swizzle (elements)

    const long ar = row0 + srow;
    const long za = zq * d.a_zq + zr * d.a_zr;
    const long a0ro = d.a0_base + za + (ar / d.a0_ic) * d.a0_os + (ar % d.a0_ic) * d.a0_is;
    long a1ro = 0;
    if (d.a1) a1ro = d.a1_base + za + (ar / d.a1_ic) * d.a1_os + (ar % d.a1_ic) * d.a1_is;
    const long bro = d.b_base + zq * d.b_zq + zr * d.b_zr + (long)(col0 + srow) * d.b_ldb;

    f32x4 acc[NT][2][2] = {};
    union { bfrag v; unsigned short h[8]; } t0, t1;

    for (int k0 = 0; k0 < d.K; k0 += 64) {
        __syncthreads();
        // ---- stage A: 16 elems at (row0+srow, k0+skq) ----
        {
            const int kg = k0 + skq;
            if (kg < d.ksplit) {
                if (d.a0_f32) {
                    const float* p = (const float*)d.a0 + a0ro + kg;
                    f32x4 x0 = *(const f32x4*)(p + 0), x1 = *(const f32x4*)(p + 4);
                    f32x4 x2 = *(const f32x4*)(p + 8), x3 = *(const f32x4*)(p + 12);
#pragma unroll
                    for (int q = 0; q < 4; ++q) {
                        t0.h[q]     = f2bf(x0[q]); t0.h[4 + q] = f2bf(x1[q]);
                        t1.h[q]     = f2bf(x2[q]); t1.h[4 + q] = f2bf(x3[q]);
                    }
                } else {
                    const unsigned short* p = (const unsigned short*)d.a0 + a0ro + kg;
                    t0.v = *(const bfrag*)(p); t1.v = *(const bfrag*)(p + 8);
                }
            } else {
                const int kl = kg - d.ksplit;
                if (d.a1_f32) {
                    const float* p = (const float*)d.a1 + a1ro + kl;
                    f32x4 x0 = *(const f32x4*)(p + 0), x1 = *(const f32x4*)(p + 4);
                    f32x4 x2 = *(const f32x4*)(p + 8), x3 = *(const f32x4*)(p + 12);
#pragma unroll
                    for (int q = 0; q < 4; ++q) {
                        t0.h[q]     = f2bf(x0[q]); t0.h[4 + q] = f2bf(x1[q]);
                        t1.h[q]     = f2bf(x2[q]); t1.h[4 + q] = f2bf(x3[q]);
                    }
                } else {
                    const unsigned short* p = (const unsigned short*)d.a1 + a1ro + kl;
                    t0.v = *(const bfrag*)(p); t1.v = *(const bfrag*)(p + 8);
                }
            }
            *(bfrag*)&As[srow * 64 + ((skq + 0) ^ swzw)] = t0.v;
            *(bfrag*)&As[srow * 64 + ((skq + 8) ^ swzw)] = t1.v;
            // ---- stage B: NT tiles, B is (N,K) row-major ----
#pragma unroll
            for (int ct = 0; ct < NT; ++ct) {
                const unsigned short* pb = d.b + bro + (long)ct * 64 * d.b_ldb + k0 + skq;
                bfrag b0 = *(const bfrag*)(pb), b1 = *(const bfrag*)(pb + 8);
                *(bfrag*)&Bs[ct * 4096 + srow * 64 + ((skq + 0) ^ swzw)] = b0;
                *(bfrag*)&Bs[ct * 4096 + srow * 64 + ((skq + 8) ^ swzw)] = b1;
            }
        }
        __syncthreads();
        // ---- compute ----
#pragma unroll
        for (int ks = 0; ks < 2; ++ks) {
            bfrag af[2];
            const int kk = ks * 32 + ((lane >> 4) << 3);
#pragma unroll
            for (int mt = 0; mt < 2; ++mt) {
                const int r = wm * 32 + mt * 16 + (lane & 15);
                af[mt] = *(const bfrag*)&As[r * 64 + (kk ^ ((r & 7) << 3))];
            }
#pragma unroll
            for (int ct = 0; ct < NT; ++ct) {
                bfrag bfm[2];
#pragma unroll
                for (int nt = 0; nt < 2; ++nt) {
                    const int r = wn * 32 + nt * 16 + (lane & 15);
                    bfm[nt] = *(const bfrag*)&Bs[ct * 4096 + r * 64 + (kk ^ ((r & 7) << 3))];
                }
#pragma unroll
                for (int mt = 0; mt < 2; ++mt)
#pragma unroll
                    for (int nt = 0; nt < 2; ++nt)
                        acc[ct][mt][nt] = __builtin_amdgcn_mfma_f32_16x16x32_bf16(
                            af[mt], bfm[nt], acc[ct][mt][nt], 0, 0, 0);
            }
        }
    }
    // ---- epilogue: C/D layout col=lane&15, row=(lane>>4)*4+j ----
    const long zc = zq * d.c_zq + zr * d.c_zr;
#pragma unroll
    for (int ct = 0; ct < NT; ++ct) {
#pragma unroll
        for (int mt = 0; mt < 2; ++mt) {
            const int rb = row0 + wm * 32 + mt * 16 + ((lane >> 4) << 2);
#pragma unroll
            for (int nt = 0; nt < 2; ++nt) {
                const int cc = col0 + ct * 64 + wn * 32 + nt * 16 + (lane & 15);
#pragma unroll
                for (int j = 0; j < 4; ++j) {
                    const long r = rb + j;
                    const long off = zc + (r / d.c_ic) * d.c_os + (r % d.c_ic) * d.c_is + cc;
                    float v = acc[ct][mt][nt][j];
                    if (d.beta == 1) v += d.c[d.c_base + off];
                    if (d.beta == 2) v += bf2f(d.cm[d.cm_base + off]);
                    if (d.c)  d.c[d.c_base + off] = v;
                    if (d.cm) d.cm[d.cm_base + off] = f2bf(v);
                    if (d.cmT) d.cmT[d.cmT_base + zc + (long)cc * 512 + r] = f2bf(v);
                }
            }
        }
    }
}

// Build bf16 operators: BopD (512x768)=[B_mat|sqrt_S_W], BopO (256x768)=[H|sqrt_S_V],
// G[0]=F, Gt[0]=F^T.
__global__ void build_ops_k(const float* F, const float* Bm, const float* H,
                            const float* sW, const float* sV,
                            unsigned short* bopd, unsigned short* bopo,
                            unsigned short* G1, unsigned short* Gt1) {
    int i = blockIdx.x * 256 + threadIdx.x;
    const int n1 = 512 * 768, n2 = 256 * 768, n3 = 512 * 512;
    if (i < n1) { int n = i / 768, k = i % 768;
        bopd[i] = f2bf(k < 256 ? Bm[n * 256 + k] : sW[n * 512 + (k - 256)]); return; }
    i -= n1;
    if (i < n2) { int o = i / 768, k = i % 768;
        bopo[i] = f2bf(k < 512 ? H[o * 512 + k] : sV[o * 256 + (k - 512)]); return; }
    i -= n2;
    if (i < n3) { G1[i] = f2bf(F[i]); return; }
    i -= n3;
    if (i < n3) { int r = i / 512, c = i % 512; Gt1[i] = f2bf(F[c * 512 + r]); }
}

// Copy rows of 512 (f32 or bf16 strided src) -> contiguous f32 + bf16 mirror.
__global__ void copy_rows_k(const void* src, int src_bf16,
                            long s_base, long s_os, long s_is, long s_ic,
                            float* dstf, unsigned short* dstm, long d_base, long n) {
    long i = (long)blockIdx.x * 256 + threadIdx.x;
    const long stride = (long)gridDim.x * 256;
    for (; i < n; i += stride) {
        const long r = i >> 9;
        const long kc = i & 511;
        const long so = s_base + (r / s_ic) * s_os + (r % s_ic) * s_is + kc;
        const float v = src_bf16 ? bf2f(((const unsigned short*)src)[so])
                                 : ((const float*)src)[so];
        dstf[d_base + i] = v;
        dstm[d_base + i] = f2bf(v);
    }
}

static GemmDesc D0() {
    GemmDesc d = {};
    d.a0_ic = 1; d.a1_ic = 1; d.c_ic = 1;
    d.zdiv = 1L << 40;
    d.ksplit = 1 << 30;
    d.b_ldb = 512; d.K = 512;
    return d;
}

extern "C" void kernel_launch(void* const* d_in, const int* in_sizes, int n_in,
                              void* d_out, int out_size, void* d_ws, size_t ws_size,
                              hipStream_t stream) {
    const float* st0 = (const float*)d_in[0];   // state   (64,512)
    const float* inp = (const float*)d_in[1];   // inputs  (64,1024,256)
    const float* Wn  = (const float*)d_in[2];   // W_noise (64,1024,512)
    const float* Vn  = (const float*)d_in[3];   // V_noise (64,1024,256)
    const float* F   = (const float*)d_in[4];   // F       (512,512)
    const float* Bm  = (const float*)d_in[5];   // B_mat   (512,256)
    const float* H   = (const float*)d_in[6];   // H       (256,512)
    const float* sW  = (const float*)d_in[7];   // sqrt_S_W(512,512)
    const float* sV  = (const float*)d_in[8];   // sqrt_S_V(256,256)

    float* states = (float*)d_out;              // (64,1024,512) f32
    float* obs    = states + 33554432L;         // (64,1024,256) f32

    const long MS = 262144;   // 512*512
    const long CB = 32768;    // 64*512 per-chunk carry block (batch x S)
    const int  NC = 64;       // chunks
    const int  CL = 16;       // chunk length
    const long TOS = 524288;  // batch stride in (b,t,s) = 1024*512
    const long COS = (long)CL * 512;  // chunk stride within a batch row = 8192

    // ws layout
    unsigned short* Smir = (unsigned short*)d_ws;       // 33,554,432 bf16 (b,t,s)
    unsigned short* G    = Smir + 33554432L;            // G[j] = F^{j+1}, j=0..15
    unsigned short* Gt   = G + 16 * MS;                 // Gt[j] = (F^{j+1})^T
    unsigned short* Qb   = Gt + 16 * MS;                // F^{32,64,128,256,512}
    unsigned short* Qtb  = Qb + 5 * MS;                 // transposes (first 4)
    unsigned short* BopD = Qtb + 4 * MS;                // 512*768
    unsigned short* BopO = BopD + 512 * 768;            // 256*768
    float* a0f = (float*)(BopO + 256 * 768);            // NC*CB f32 carries
    float* a1f = a0f + NC * CB;
    unsigned short* a0m = (unsigned short*)(a1f + NC * CB);
    unsigned short* a1m = a0m + NC * CB;
    (void)ws_size; (void)in_sizes; (void)n_in; (void)out_size;

    auto L1 = [&](const GemmDesc& d, int gx, int gy, int gz) {
        gemm_k<1><<<dim3(gx, gy, gz), dim3(256), 0, stream>>>(d);
    };
    auto L4 = [&](const GemmDesc& d, int gx, int gy, int gz) {
        gemm_k<4><<<dim3(gx, gy, gz), dim3(256), 0, stream>>>(d);
    };

    // 1) operators + F, F^T
    build_ops_k<<<dim3(4352), dim3(256), 0, stream>>>(F, Bm, H, sW, sV, BopD, BopO, G, Gt);

    // 2) powers G[m..2m-1] = G[j] @ (Gt[m-1])^T = F^{j+1+m}; transposes in-epilogue.
    for (int m = 1; m <= 8; m <<= 1) {
        GemmDesc d = D0();
        d.a0 = G; d.a0_os = 512; d.a_zr = MS;
        d.b = Gt; d.b_base = (long)(m - 1) * MS;
        d.cm = G;  d.cm_base  = (long)m * MS; d.c_os = 512; d.c_zr = MS;
        d.cmT = Gt; d.cmT_base = (long)m * MS;
        L1(d, 8, 8, m);
    }
    // Q chain: Qb[0]=F^32=G[15]@F^16, then squares. withT for all but last.
    {
        auto ql = [&](const unsigned short* A, long ab, const unsigned short* B, long bb,
                      long cb, bool withT) {
            GemmDesc d = D0();
            d.a0 = A; d.a0_base = ab; d.a0_os = 512;
            d.b = B; d.b_base = bb;
            d.cm = Qb; d.cm_base = cb; d.c_os = 512;
            if (withT) { d.cmT = Qtb; d.cmT_base = cb; }
            L1(d, 8, 8, 1);
        };
        ql(G, 15 * MS, Gt, 15 * MS, 0, true);        // F^32
        ql(Qb, 0, Qtb, 0, MS, true);                 // F^64
        ql(Qb, MS, Qtb, MS, 2 * MS, true);           // F^128
        ql(Qb, 2 * MS, Qtb, 2 * MS, 3 * MS, true);   // F^256
        ql(Qb, 3 * MS, Qtb, 3 * MS, 4 * MS, false);  // F^512
    }

    // 3) drive = [inputs | W_noise] @ BopD^T -> Smir (bf16 only)
    {
        GemmDesc d = D0();
        d.a0 = inp; d.a0_f32 = 1; d.a0_os = 256;
        d.a1 = Wn;  d.a1_f32 = 1; d.a1_os = 512;
        d.ksplit = 256; d.K = 768;
        d.b = BopD; d.b_ldb = 768;
        d.cm = Smir; d.c_os = 512;
        L4(d, 2, 1024, 1);
    }

    // 4) phase 1: local scans in bf16, 15 sequential steps over all chunks.
    //    rows r -> (b = r/64, c = r%64); Smir elem = b*TOS + c*COS + k*512 + s
    for (int k = 1; k < CL; ++k) {
        GemmDesc d = D0();
        d.a0 = Smir; d.a0_base = (long)(k - 1) * 512;
        d.a0_ic = NC; d.a0_is = COS; d.a0_os = TOS;
        d.b = G;  // F
        d.c_base = (long)k * 512;
        d.c_ic = NC; d.c_is = COS; d.c_os = TOS;
        d.beta = 2;                       // += drive (bf16, in place)
        d.cm = Smir; d.cm_base = (long)k * 512;
        L1(d, 8, 64, 1);
    }

    // 5) carries e: e[0]=s0 (f32), e[c]=local[c-1, CL-1] (bf16 from Smir)
    copy_rows_k<<<dim3(128), dim3(256), 0, stream>>>(
        st0, 0, 0, 512, 0, 1, a0f, a0m, 0, CB);
    copy_rows_k<<<dim3(2048), dim3(256), 0, stream>>>(
        Smir, 1, (long)(CL - 1) * 512, COS, TOS, NC, a0f, a0m, CB, (long)(NC - 1) * CB);

    // 6) Kogge-Stone: a_c += a_{c-s} @ (F^{CL*s})^T, s=1,2,...,32
    float* cur = a0f; unsigned short* curm = a0m;
    float* nxt = a1f; unsigned short* nxtm = a1m;
    for (int s = 1; s <= 32; s <<= 1) {
        copy_rows_k<<<dim3(2048), dim3(256), 0, stream>>>(
            cur, 0, 0, 512, 0, 1, nxt, nxtm, 0, (long)NC * CB);
        GemmDesc d = D0();
        d.a0 = curm; d.a0_os = 512; d.a_zr = CB;
        const unsigned short* qm; long qb;
        if (s == 1) { qm = G; qb = 15 * MS; }            // F^16
        else        { qm = Qb; qb = (long)(__builtin_ctz(s) - 1) * MS; }  // F^{16s}
        d.b = qm; d.b_base = qb;
        d.c = nxt; d.c_base = (long)s * CB; d.c_os = 512; d.c_zr = CB; d.beta = 1;
        d.cm = nxtm; d.cm_base = (long)s * CB;
        L1(d, 8, 1, NC - s);
        float* tf = cur; cur = nxt; nxt = tf;
        unsigned short* tm = curm; curm = nxtm; nxtm = tm;
    }

    // 7) phase 3: states[c,k] = local[c,k] + init_c @ (F^{k+1})^T; write f32 + mirror.
    //    z = c*CL + k
    {
        GemmDesc d = D0();
        d.a0 = curm; d.a0_os = 512; d.a_zq = CB; d.zdiv = CL;
        d.b = G; d.b_zr = MS;
        d.c = states; d.c_zq = COS; d.c_zr = 512; d.c_os = TOS;
        d.beta = 2;                       // += local (bf16 from Smir)
        d.cm = Smir; d.cm_base = 0; d.c_base = 0;
        L4(d, 2, 1, NC * CL);
    }

    // 8) obs = [states_bf16 | V_noise] @ BopO^T
    {
        GemmDesc d = D0();
        d.a0 = Smir; d.a0_os = 512;
        d.a1 = Vn; d.a1_f32 = 1; d.a1_os = 256;
        d.ksplit = 512; d.K = 768;
        d.b = BopO; d.b_ldb = 768;
        d.c = obs; d.c_os = 256;
        L4(d, 1, 1024, 1);
    }
}